// Round 4
// baseline (692.297 us; speedup 1.0000x reference)
//
#include <hip/hip_runtime.h>
#include <stdint.h>

#define N_TOK 7200
#define N_PAD 7296      // 57*128
#define K_CODE 8912
#define K_PAD 8960      // 70*128
#define N_KT 70
#define N_MT 57
#define MID 256
#define C_DIM 768
#define INV_TEMP (1.0f/0.07f)
#define INV_ETEMP 100.0f
#define MARGIN 0.02f
#define CAND_CAP 64
#define EPS_N 1e-12f
#define LDT 136          // LDS row stride (shorts) for 128-col tile +8 pad

typedef __attribute__((ext_vector_type(8))) short short8;   // 8 bf16 (4 VGPRs)
typedef __attribute__((ext_vector_type(4))) float f32x4;

__device__ __forceinline__ unsigned short f2bf(float f) {
    unsigned u = __float_as_uint(f);
    u += 0x7fffu + ((u >> 16) & 1u);   // round-to-nearest-even
    return (unsigned short)(u >> 16);
}
__device__ __forceinline__ float bf2f(unsigned short h) {
    return __uint_as_float(((unsigned)h) << 16);
}

// ---------------- init: zero accumulators (ws is poisoned 0xAA each call) ---
__global__ void k_init(float* ap_acc, int* used, float* acc4, int* ccnt) {
    int i = blockIdx.x * 256 + threadIdx.x;
    if (i < K_CODE) { ap_acc[i] = 0.f; used[i] = 0; }
    if (i < N_TOK) ccnt[i] = 0;
    if (i < 4) acc4[i] = 0.f;
}

// ---------------- W_down -> transposed bf16 hi/lo splits ---------------------
__global__ void k_wsplit(const float* __restrict__ W,
                         unsigned short* __restrict__ wt_h,
                         unsigned short* __restrict__ wt_l) {
    int i = blockIdx.x * 256 + threadIdx.x;
    if (i >= C_DIM * MID) return;
    int c = i / MID, t = i % MID;
    float v = W[i];
    unsigned short h = f2bf(v);
    unsigned short l = f2bf(v - bf2f(h));
    wt_h[t * C_DIM + c] = h;
    wt_l[t * C_DIM + c] = l;
}

// ---------------- embedding l2norm -> en (f32) + en_h (bf16) ----------------
__global__ void k_ennorm(const float* __restrict__ emb,
                         float* __restrict__ en,
                         unsigned short* __restrict__ en_h) {
    int n = blockIdx.x, t = threadIdx.x;
    float v = emb[n * MID + t];
    __shared__ float sb[256];
    sb[t] = v * v; __syncthreads();
    for (int s = 128; s > 0; s >>= 1) { if (t < s) sb[t] += sb[t + s]; __syncthreads(); }
    float nn = sqrtf(sb[0]);
    float o = v / fmaxf(nn, EPS_N);
    en[n * MID + t] = o;
    en_h[n * MID + t] = f2bf(o);
}

// ---------------- z = x @ W_down via bf16x3 MFMA (fp32-quality) -------------
__global__ __launch_bounds__(256) void k_zgemm(const float* __restrict__ x,
                                               const unsigned short* __restrict__ wt_h,
                                               const unsigned short* __restrict__ wt_l,
                                               float* __restrict__ zbuf) {
    __shared__ unsigned short ls[4 * 64 * 72];
    unsigned short* xh = ls;
    unsigned short* xl = ls + 64 * 72;
    unsigned short* wh = ls + 2 * 64 * 72;
    unsigned short* wl = ls + 3 * 64 * 72;
    int tid = threadIdx.x;
    int m0 = blockIdx.y * 64;
    int t0 = blockIdx.x * 64;
    int lane = tid & 63, wv = tid >> 6;
    int quad = lane >> 4, l15 = lane & 15;
    int mrow0 = (wv >> 1) * 32, ncol0 = (wv & 1) * 32;
    f32x4 acc[2][2] = {};

    for (int ch = 0; ch < 12; ch++) {
        int c0 = ch * 64;
        for (int it = 0; it < 4; it++) {
            int r = it * 16 + (tid >> 4);
            int cq = tid & 15;
            float4 v = make_float4(0.f, 0.f, 0.f, 0.f);
            int gr = m0 + r;
            if (gr < N_TOK) v = ((const float4*)x)[(size_t)gr * (C_DIM / 4) + (c0 >> 2) + cq];
            unsigned short h0 = f2bf(v.x), h1 = f2bf(v.y), h2 = f2bf(v.z), h3 = f2bf(v.w);
            ushort4 hh = make_ushort4(h0, h1, h2, h3);
            ushort4 ll = make_ushort4(f2bf(v.x - bf2f(h0)), f2bf(v.y - bf2f(h1)),
                                      f2bf(v.z - bf2f(h2)), f2bf(v.w - bf2f(h3)));
            *((ushort4*)&xh[r * 72 + cq * 4]) = hh;
            *((ushort4*)&xl[r * 72 + cq * 4]) = ll;
        }
        for (int it = 0; it < 2; it++) {
            int r = it * 32 + (tid >> 3);
            int cq = tid & 7;
            uint4 vh = ((const uint4*)wt_h)[(size_t)(t0 + r) * (C_DIM / 8) + (c0 >> 3) + cq];
            uint4 vl = ((const uint4*)wt_l)[(size_t)(t0 + r) * (C_DIM / 8) + (c0 >> 3) + cq];
            *((uint4*)&wh[r * 72 + cq * 8]) = vh;
            *((uint4*)&wl[r * 72 + cq * 8]) = vl;
        }
        __syncthreads();
        for (int ks = 0; ks < 2; ks++) {
            int co = ks * 32 + quad * 8;
            short8 ah0 = *((const short8*)&xh[(mrow0 + l15) * 72 + co]);
            short8 ah1 = *((const short8*)&xh[(mrow0 + 16 + l15) * 72 + co]);
            short8 al0 = *((const short8*)&xl[(mrow0 + l15) * 72 + co]);
            short8 al1 = *((const short8*)&xl[(mrow0 + 16 + l15) * 72 + co]);
            short8 bh0 = *((const short8*)&wh[(ncol0 + l15) * 72 + co]);
            short8 bh1 = *((const short8*)&wh[(ncol0 + 16 + l15) * 72 + co]);
            short8 bl0 = *((const short8*)&wl[(ncol0 + l15) * 72 + co]);
            short8 bl1 = *((const short8*)&wl[(ncol0 + 16 + l15) * 72 + co]);
            acc[0][0] = __builtin_amdgcn_mfma_f32_16x16x32_bf16(ah0, bh0, acc[0][0], 0, 0, 0);
            acc[0][1] = __builtin_amdgcn_mfma_f32_16x16x32_bf16(ah0, bh1, acc[0][1], 0, 0, 0);
            acc[1][0] = __builtin_amdgcn_mfma_f32_16x16x32_bf16(ah1, bh0, acc[1][0], 0, 0, 0);
            acc[1][1] = __builtin_amdgcn_mfma_f32_16x16x32_bf16(ah1, bh1, acc[1][1], 0, 0, 0);
            acc[0][0] = __builtin_amdgcn_mfma_f32_16x16x32_bf16(ah0, bl0, acc[0][0], 0, 0, 0);
            acc[0][1] = __builtin_amdgcn_mfma_f32_16x16x32_bf16(ah0, bl1, acc[0][1], 0, 0, 0);
            acc[1][0] = __builtin_amdgcn_mfma_f32_16x16x32_bf16(ah1, bl0, acc[1][0], 0, 0, 0);
            acc[1][1] = __builtin_amdgcn_mfma_f32_16x16x32_bf16(ah1, bl1, acc[1][1], 0, 0, 0);
            acc[0][0] = __builtin_amdgcn_mfma_f32_16x16x32_bf16(al0, bh0, acc[0][0], 0, 0, 0);
            acc[0][1] = __builtin_amdgcn_mfma_f32_16x16x32_bf16(al0, bh1, acc[0][1], 0, 0, 0);
            acc[1][0] = __builtin_amdgcn_mfma_f32_16x16x32_bf16(al1, bh0, acc[1][0], 0, 0, 0);
            acc[1][1] = __builtin_amdgcn_mfma_f32_16x16x32_bf16(al1, bh1, acc[1][1], 0, 0, 0);
        }
        __syncthreads();
    }
    for (int i = 0; i < 2; i++)
        for (int j = 0; j < 2; j++)
            for (int r = 0; r < 4; r++) {
                int gr = m0 + mrow0 + i * 16 + quad * 4 + r;
                int gc = t0 + ncol0 + j * 16 + l15;
                if (gr < N_TOK) zbuf[(size_t)gr * MID + gc] = acc[i][j][r];
            }
}

// ---------------- z + b -> l2norm -> zn (in place) + zn_h -------------------
__global__ void k_znorm(float* __restrict__ zbuf, const float* __restrict__ b_down,
                        unsigned short* __restrict__ zn_h) {
    int n = blockIdx.x, t = threadIdx.x;
    float v = zbuf[(size_t)n * MID + t] + b_down[t];
    __shared__ float sb[256];
    sb[t] = v * v; __syncthreads();
    for (int s = 128; s > 0; s >>= 1) { if (t < s) sb[t] += sb[t + s]; __syncthreads(); }
    float nn = sqrtf(sb[0]);
    float o = v / fmaxf(nn, EPS_N);
    zbuf[(size_t)n * MID + t] = o;
    zn_h[(size_t)n * MID + t] = f2bf(o);
}

// ---------------- d-GEMM, 128x128 tiles, two passes, no d materialization ---
// PASS 1: per-(row, 128-col-tile) partials {min, st, s1, s2} -> part4
// PASS 2: probs -> out1 (from regs), avg_probs col sums, element candidates
template<int PASS>
__global__ __launch_bounds__(256) void k_dpass(const unsigned short* __restrict__ zn_h,
                                               const unsigned short* __restrict__ en_h,
                                               float4* __restrict__ part4,
                                               const float* __restrict__ rs_m,
                                               const float* __restrict__ rs_ist,
                                               const float* __restrict__ rs_is1,
                                               float* __restrict__ ap_acc,
                                               float* __restrict__ out1,
                                               int* __restrict__ ccnt,
                                               int* __restrict__ cand) {
    __shared__ __align__(16) unsigned short ab_s[2 * 128 * LDT];   // 69632 B
    __shared__ float rs_s[3 * 128];
    unsigned short* a_s = ab_s;
    unsigned short* b_s = ab_s + 128 * LDT;
    int tid = threadIdx.x;
    int kt = blockIdx.x, mt = blockIdx.y;
    int m0 = mt * 128, k0 = kt * 128;
    int lane = tid & 63, w = tid >> 6;
    int quad = lane >> 4, l15 = lane & 15;
    int wrow = (w >> 1) * 64, wcol = (w & 1) * 64;
    f32x4 acc[4][4] = {};

    if (PASS == 2 && tid < 128) {
        int gr = m0 + tid;
        bool ok = gr < N_TOK;
        rs_s[tid]       = ok ? rs_m[gr]   : 0.f;
        rs_s[128 + tid] = ok ? rs_ist[gr] : 0.f;
        rs_s[256 + tid] = ok ? rs_is1[gr] : 0.f;
    }

    for (int ch = 0; ch < 2; ch++) {
        #pragma unroll
        for (int it = 0; it < 8; it++) {
            int lin = it * 256 + tid;
            int r = lin >> 4, c16 = lin & 15;
            uint4 va = ((const uint4*)zn_h)[(size_t)(m0 + r) * 32 + ch * 16 + c16];
            uint4 vb = ((const uint4*)en_h)[(size_t)(k0 + r) * 32 + ch * 16 + c16];
            *((uint4*)&a_s[r * LDT + c16 * 8]) = va;
            *((uint4*)&b_s[r * LDT + c16 * 8]) = vb;
        }
        __syncthreads();
        #pragma unroll
        for (int ks = 0; ks < 4; ks++) {
            int co = ks * 32 + quad * 8;
            short8 af[4], bfr[4];
            #pragma unroll
            for (int i = 0; i < 4; i++) af[i]  = *((const short8*)&a_s[(wrow + i * 16 + l15) * LDT + co]);
            #pragma unroll
            for (int j = 0; j < 4; j++) bfr[j] = *((const short8*)&b_s[(wcol + j * 16 + l15) * LDT + co]);
            #pragma unroll
            for (int i = 0; i < 4; i++)
                #pragma unroll
                for (int j = 0; j < 4; j++)
                    acc[i][j] = __builtin_amdgcn_mfma_f32_16x16x32_bf16(af[i], bfr[j], acc[i][j], 0, 0, 0);
        }
        __syncthreads();
    }

    // convert acc -> masked d in place
    bool okc[4];
    #pragma unroll
    for (int j = 0; j < 4; j++) okc[j] = (k0 + wcol + j * 16 + l15) < K_CODE;
    #pragma unroll
    for (int i = 0; i < 4; i++)
        #pragma unroll
        for (int j = 0; j < 4; j++)
            #pragma unroll
            for (int r = 0; r < 4; r++)
                acc[i][j][r] = okc[j] ? (2.f - 2.f * acc[i][j][r]) : 1e30f;

    if (PASS == 1) {
        // per-lane partial (4 cols) per row -> LDS [128][33] float4 (reuses ab_s)
        float4* p_s = (float4*)ab_s;
        #pragma unroll
        for (int i = 0; i < 4; i++)
            #pragma unroll
            for (int r = 0; r < 4; r++) {
                int lr = wrow + i * 16 + quad * 4 + r;
                float v0 = acc[i][0][r], v1 = acc[i][1][r], v2 = acc[i][2][r], v3 = acc[i][3][r];
                float vmin = fminf(fminf(v0, v1), fminf(v2, v3));
                float st = 0.f, s1 = 0.f, s2 = 0.f;
                #pragma unroll
                for (int j = 0; j < 4; j++) {
                    float dd = vmin - acc[i][j][r];
                    st += __expf(dd * INV_TEMP);
                    float te = dd * INV_ETEMP;
                    float e = __expf(te);
                    s1 += e; s2 += e * te;
                }
                p_s[lr * 33 + (w & 1) * 16 + l15] = make_float4(vmin, st, s1, s2);
            }
        __syncthreads();
        if (tid < 128) {
            const float4* rowp = (const float4*)ab_s + tid * 33;
            float m = 1e30f;
            #pragma unroll
            for (int p = 0; p < 32; p++) m = fminf(m, rowp[p].x);
            float st = 0.f, s1 = 0.f, s2 = 0.f;
            #pragma unroll
            for (int p = 0; p < 32; p++) {
                float4 v = rowp[p];
                if (v.x < 1e29f) {
                    float dT = (m - v.x) * INV_TEMP;
                    st += __expf(dT) * v.y;
                    float dE = (m - v.x) * INV_ETEMP;
                    float e = __expf(dE);
                    s1 += e * v.z;
                    s2 += e * (v.w + dE * v.z);
                }
            }
            int gr = m0 + tid;
            if (gr < N_TOK) part4[(size_t)gr * N_KT + kt] = make_float4(m, st, s1, s2);
        }
    } else {
        float colsum[4] = {0.f, 0.f, 0.f, 0.f};
        #pragma unroll
        for (int i = 0; i < 4; i++)
            #pragma unroll
            for (int r = 0; r < 4; r++) {
                int lr = wrow + i * 16 + quad * 4 + r;
                int gr = m0 + lr;
                if (gr >= N_TOK) continue;
                float mm = rs_s[lr], tt = rs_s[128 + lr], o1 = rs_s[256 + lr];
                float thr = mm + MARGIN;
                float* orow = out1 + (size_t)gr * K_CODE;
                #pragma unroll
                for (int j = 0; j < 4; j++) {
                    if (!okc[j]) continue;
                    int gc = k0 + wcol + j * 16 + l15;
                    float dv = acc[i][j][r];
                    if (dv <= thr) {
                        int p = atomicAdd(&ccnt[gr], 1);
                        if (p < CAND_CAP) cand[gr * CAND_CAP + p] = gc;
                    }
                    orow[gc] = __expf((mm - dv) * INV_TEMP) * tt;
                    colsum[j] += __expf((mm - dv) * INV_ETEMP) * o1;
                }
            }
        // reduce colsum across the 4 quads (lanes with equal l15)
        #pragma unroll
        for (int j = 0; j < 4; j++) {
            colsum[j] += __shfl_xor(colsum[j], 16);
            colsum[j] += __shfl_xor(colsum[j], 32);
        }
        if (quad == 0) {
            #pragma unroll
            for (int j = 0; j < 4; j++) {
                int gc = k0 + wcol + j * 16 + l15;
                if (gc < K_CODE) atomicAdd(&ap_acc[gc], colsum[j]);
            }
        }
    }
}

// ---------------- combine 70 tile-partials per row --------------------------
__global__ void k_combine(const float4* __restrict__ part4,
                          float* __restrict__ rs_m, float* __restrict__ rs_ist,
                          float* __restrict__ rs_is1,
                          float* __restrict__ acc4) {
    int sub = threadIdx.x >> 6;
    int row = blockIdx.x * 4 + sub;
    int l = threadIdx.x & 63;
    float4 pv[2];
    float m = 1e30f;
    #pragma unroll
    for (int c = 0; c < 2; c++) {
        int t = l + c * 64;
        pv[c] = (t < N_KT) ? part4[(size_t)row * N_KT + t] : make_float4(1e30f, 0.f, 0.f, 0.f);
        m = fminf(m, pv[c].x);
    }
    #pragma unroll
    for (int s = 1; s < 64; s <<= 1) m = fminf(m, __shfl_xor(m, s));
    float st = 0.f, s1 = 0.f, s2 = 0.f;
    #pragma unroll
    for (int c = 0; c < 2; c++) {
        float mb = pv[c].x;
        int t = l + c * 64;
        if (t < N_KT && mb < 1e29f) {
            float dT = (m - mb) * INV_TEMP;
            st += __expf(dT) * pv[c].y;
            float dE = (m - mb) * INV_ETEMP;
            float e = __expf(dE);
            s1 += e * pv[c].z;
            s2 += e * (pv[c].w + dE * pv[c].z);
        }
    }
    #pragma unroll
    for (int s = 1; s < 64; s <<= 1) {
        st += __shfl_xor(st, s);
        s1 += __shfl_xor(s1, s);
        s2 += __shfl_xor(s2, s);
    }
    if (l == 0) {
        rs_m[row] = m;
        rs_ist[row] = 1.f / st;
        rs_is1[row] = 1.f / s1;
        atomicAdd(&acc4[1], s2 / s1 - __logf(s1));
    }
}

// ---------------- exact fp32 argmin over element candidates + z_q_ste -------
__global__ void k_refine(const float* __restrict__ zn, const float* __restrict__ en,
                         const int* __restrict__ ccnt, const int* __restrict__ cand,
                         int* __restrict__ idxb, int* __restrict__ used,
                         float* __restrict__ acc4, float* __restrict__ out0) {
    int n = blockIdx.x * 4 + (threadIdx.x >> 6);
    int lane = threadIdx.x & 63;
    if (n >= N_TOK) return;
    int cnt = ccnt[n];
    if (cnt > CAND_CAP) cnt = CAND_CAP;
    float4 a = ((const float4*)(zn + (size_t)n * MID))[lane];
    float best = 1e30f; int bj = K_CODE;
    for (int c = 0; c < cnt; c++) {
        int code = cand[n * CAND_CAP + c];
        float4 b = ((const float4*)(en + (size_t)code * MID))[lane];
        float s = a.x * b.x + a.y * b.y + a.z * b.z + a.w * b.w;
        #pragma unroll
        for (int off = 1; off < 64; off <<= 1) s += __shfl_xor(s, off);
        float dist = 2.f - 2.f * s;
        if (dist < best || (dist == best && code < bj)) { best = dist; bj = code; }
    }
    float4 b = ((const float4*)(en + (size_t)bj * MID))[lane];
    ((float4*)(out0 + (size_t)n * MID))[lane] = b;
    float dx = b.x - a.x, dy = b.y - a.y, dz = b.z - a.z, dw = b.w - a.w;
    float sq = dx * dx + dy * dy + dz * dz + dw * dw;
    #pragma unroll
    for (int off = 32; off > 0; off >>= 1) sq += __shfl_down(sq, off);
    if (lane == 0) {
        idxb[n] = bj;
        used[bj] = 1;
        atomicAdd(&acc4[0], sq);
    }
}

// ---------------- final scalars ---------------------------------------------
__global__ void k_scal(const int* __restrict__ used, const float* __restrict__ ap_acc,
                       const float* __restrict__ acc4, float* __restrict__ outs) {
    int t = threadIdx.x;
    float uSum = 0.f, aeSum = 0.f;
    for (int k = t; k < K_CODE; k += 256) {
        uSum += (float)used[k];
        float ap = ap_acc[k] * (1.0f / (float)N_TOK);
        aeSum += ap * __logf(ap + 1e-5f);
    }
    __shared__ float sb[256];
    sb[t] = uSum; __syncthreads();
    for (int s = 128; s > 0; s >>= 1) { if (t < s) sb[t] += sb[t + s]; __syncthreads(); }
    uSum = sb[0];
    __syncthreads(); sb[t] = aeSum; __syncthreads();
    for (int s = 128; s > 0; s >>= 1) { if (t < s) sb[t] += sb[t + s]; __syncthreads(); }
    aeSum = sb[0];
    if (t == 0) {
        outs[0] = uSum / (float)K_CODE;
        float vq = acc4[0] / (float)((size_t)N_TOK * MID);
        outs[1] = vq;
        outs[2] = vq;
        outs[3] = -(acc4[1] / (float)N_TOK) + aeSum;
    }
}

extern "C" void kernel_launch(void* const* d_in, const int* in_sizes, int n_in,
                              void* d_out, int out_size, void* d_ws, size_t ws_size,
                              hipStream_t stream) {
    const float* x   = (const float*)d_in[0];
    const float* W   = (const float*)d_in[1];
    const float* b   = (const float*)d_in[2];
    const float* emb = (const float*)d_in[3];

    float* out  = (float*)d_out;
    float* out0 = out;                                                  // [7200*256]
    float* out1 = out + (size_t)N_TOK * MID;                            // probs
    float* outs = out + (size_t)N_TOK * MID + (size_t)N_TOK * K_CODE;   // 4 scalars

    char* w = (char*)d_ws;
    size_t off = 0;
    auto carve = [&](size_t bytes) { void* p = w + off; off += (bytes + 255) & ~(size_t)255; return p; };
    float*          zn    = (float*)         carve((size_t)N_PAD * MID * 4);
    float*          en    = (float*)         carve((size_t)K_PAD * MID * 4);
    unsigned short* zn_h  = (unsigned short*)carve((size_t)N_PAD * MID * 2);
    unsigned short* en_h  = (unsigned short*)carve((size_t)K_PAD * MID * 2);
    unsigned short* wt_h  = (unsigned short*)carve((size_t)MID * C_DIM * 2);
    unsigned short* wt_l  = (unsigned short*)carve((size_t)MID * C_DIM * 2);
    float4*         part4 = (float4*)        carve((size_t)N_TOK * N_KT * 16);
    float*          rs_m  = (float*)         carve((size_t)N_TOK * 4);
    float*          rs_ist= (float*)         carve((size_t)N_TOK * 4);
    float*          rs_is1= (float*)         carve((size_t)N_TOK * 4);
    int*            ccnt  = (int*)           carve((size_t)N_TOK * 4);
    int*            cand  = (int*)           carve((size_t)N_TOK * CAND_CAP * 4);
    int*            idxb  = (int*)           carve((size_t)N_TOK * 4);
    float*          ap_acc= (float*)         carve((size_t)K_CODE * 4);
    int*            used  = (int*)           carve((size_t)K_CODE * 4);
    float*          acc4  = (float*)         carve(16);
    (void)ws_size; (void)in_sizes; (void)n_in; (void)out_size;

    k_init   <<<35, 256, 0, stream>>>(ap_acc, used, acc4, ccnt);
    k_wsplit <<<(C_DIM * MID + 255) / 256, 256, 0, stream>>>(W, wt_h, wt_l);
    k_ennorm <<<K_CODE, 256, 0, stream>>>(emb, en, en_h);
    k_zgemm  <<<dim3(4, 113), 256, 0, stream>>>(x, wt_h, wt_l, zn);
    k_znorm  <<<N_TOK, 256, 0, stream>>>(zn, b, zn_h);
    k_dpass<1><<<dim3(N_KT, N_MT), 256, 0, stream>>>(zn_h, en_h, part4, rs_m, rs_ist, rs_is1, ap_acc, out1, ccnt, cand);
    k_combine<<<N_TOK / 4, 256, 0, stream>>>(part4, rs_m, rs_ist, rs_is1, acc4);
    k_dpass<2><<<dim3(N_KT, N_MT), 256, 0, stream>>>(zn_h, en_h, part4, rs_m, rs_ist, rs_is1, ap_acc, out1, ccnt, cand);
    k_refine <<<N_TOK / 4, 256, 0, stream>>>(zn, en, ccnt, cand, idxb, used, acc4, out0);
    k_scal   <<<1, 256, 0, stream>>>(used, ap_acc, acc4, outs);
}